// Round 10
// baseline (10578.230 us; speedup 1.0000x reference)
//
#include <hip/hip_runtime.h>

typedef unsigned int u32;
typedef unsigned short u16;
typedef unsigned long long u64;

#define T_STEPS 2048
#define BATCH   32
#define HID     512
#define INDIM   128
#define OUTD    128
#define NG      2048
#define L0_WGS  32
#define L1_WGS  32
#define FC_WGS  2
#define NWG     (L0_WGS + L1_WGS + FC_WGS)
#define NTHR    512
#define BH      (BATCH * HID)

#define HID_OFF 8388608           // 32*2048*128
#define CN_OFF  8396800           // + 2*32*128

// ws layout (bytes) — byte-identical to v5
#define WS_FLAGS   0                         // flags, 64B stride (16 KB reserved)
#define WS_H0RING  16384
#define WS_H1RING  (WS_H0RING + 131072)      // 4*32*512*2
#define WS_BIAS0   (WS_H1RING + 131072)
#define WS_BIAS1   (WS_BIAS0 + 8192)
#define WS_WFC     (WS_BIAS1 + 8192)         // 2 * 32768 u16
#define WS_WL0     (WS_WFC + 131072)         // 32 * 40960 u16
#define WS_WL1     (WS_WL0 + 2621440)        // 32 * 65536 u16
#define WS_XBF     (WS_WL1 + 4194304)        // 32*2048*128 u16

typedef __bf16 bf16x8 __attribute__((ext_vector_type(8)));
typedef float  f32x4  __attribute__((ext_vector_type(4)));
typedef unsigned int u32x4 __attribute__((ext_vector_type(4)));

__device__ __forceinline__ u16 f2bf(float f) {
    u32 u = __float_as_uint(f);
    u32 r = u + 0x7FFFu + ((u >> 16) & 1u);
    return (u16)(r >> 16);
}

union UB2 { u32x4 u; bf16x8 b; };
__device__ __forceinline__ bf16x8 as_bf(u32x4 u) { UB2 x; x.u = u; return x.b; }

__device__ __forceinline__ u32 relu2(u32 u) {
    u32 lo = (u & 0x8000u)     ? 0u : (u & 0xFFFFu);
    u32 hi = (u & 0x80000000u) ? 0u : (u & 0xFFFF0000u);
    return lo | hi;
}

// 16B LLC-bypass load (sc0 sc1). NON-atomic; caller waits vmcnt before use.
__device__ __forceinline__ u32x4 ld16_llc(const void* p) {
    u32x4 r;
    asm volatile("global_load_dwordx4 %0, %1, off sc0 sc1"
                 : "=v"(r) : "v"(p) : "memory");
    return r;
}
__device__ __forceinline__ void wait_vm0() {
    asm volatile("s_waitcnt vmcnt(0)" ::: "memory");
    __builtin_amdgcn_sched_barrier(0);
}
__device__ __forceinline__ void wait_vm4() {     // 4 newest loads may remain
    asm volatile("s_waitcnt vmcnt(4)" ::: "memory");
    __builtin_amdgcn_sched_barrier(0);
}
__device__ __forceinline__ void vm0() {
    asm volatile("s_waitcnt vmcnt(0)" ::: "memory");
}

// ---------------- prep kernels ----------------

__global__ void k_zero(u32* dst, int n) {
    int i = blockIdx.x * blockDim.x + threadIdx.x;
    if (i < n) dst[i] = 0u;
}

__global__ void k_bias(const float* __restrict__ bih0, const float* __restrict__ bhh0,
                       const float* __restrict__ bih1, const float* __restrict__ bhh1,
                       float* __restrict__ bias0, float* __restrict__ bias1) {
    int i = blockIdx.x * blockDim.x + threadIdx.x;
    if (i < NG) {
        int orig = (i & 3) * HID + (i >> 2);
        bias0[i] = bih0[orig] + bhh0[orig];
        bias1[i] = bih1[orig] + bhh1[orig];
    }
}

__global__ void k_xconv(const float* __restrict__ x, u16* __restrict__ xbf) {
    int i = blockIdx.x * blockDim.x + threadIdx.x;   // exactly 2097152 threads
    float4 v = reinterpret_cast<const float4*>(x)[i];
    u32 lo = (u32)f2bf(v.x) | ((u32)f2bf(v.y) << 16);
    u32 hi = (u32)f2bf(v.z) | ((u32)f2bf(v.w) << 16);
    reinterpret_cast<uint2*>(xbf)[i] = make_uint2(lo, hi);
}

// 64-col LDS-ready layout per WG: [ks][kb(4)][n(64)][8], value = W[p=wg*64+n][k=32ks+8kb+j]
__global__ void k_wconv(const float* __restrict__ wih0, const float* __restrict__ whh0,
                        const float* __restrict__ wih1, const float* __restrict__ whh1,
                        const float* __restrict__ fcw,
                        u16* __restrict__ wl0, u16* __restrict__ wl1, u16* __restrict__ wfc) {
    int i = blockIdx.x * blockDim.x + threadIdx.x;   // exactly 3473408 threads
    if (i < 32 * 40960) {                            // layer0: 64 cols x K=640
        int wg = i / 40960, r = i % 40960;
        int ks = r / 2048, kb = (r % 2048) / 512, n = (r % 512) / 8, j = r % 8;
        int k = ks * 32 + kb * 8 + j;
        int p = wg * 64 + n;
        int orig = (p & 3) * HID + (p >> 2);
        float v = (k < HID) ? whh0[orig * HID + k] : wih0[orig * INDIM + (k - HID)];
        wl0[i] = f2bf(v);
        return;
    }
    int i1 = i - 32 * 40960;
    if (i1 < 32 * 65536) {                           // layer1: 64 cols x K=1024
        int wg = i1 / 65536, r = i1 % 65536;
        int ks = r / 2048, kb = (r % 2048) / 512, n = (r % 512) / 8, j = r % 8;
        int k = ks * 32 + kb * 8 + j;
        int p = wg * 64 + n;
        int orig = (p & 3) * HID + (p >> 2);
        float v = (k < HID) ? wih1[orig * HID + k] : whh1[orig * HID + (k - HID)];
        wl1[i1] = f2bf(v);
        return;
    }
    int i2 = i1 - 32 * 65536;
    if (i2 < 2 * 32768) {                            // fc: 64 cols x K=512
        int wg = i2 / 32768, r = i2 % 32768;
        int ks = r / 2048, kb = (r % 2048) / 512, n = (r % 512) / 8, j = r % 8;
        int k = ks * 32 + kb * 8 + j;
        int o = wg * 64 + n;
        wfc[i2] = f2bf(fcw[o * HID + k]);
    }
}

// ---------------- persistent fused LSTM ----------------
//
// v5 protocol (proven), FATTER WGs: 64 output cols, 512 threads, 8 waves
// (mt in {0,1} batch-half x nc in {0..3} col-tile).  66 WGs instead of 132
// => aggregate LLC broadcast requests/step halve (400k -> 200k) — the only
// lever that has ever moved step time (v0->v5: 2x; R1: -2x; R6/R7/R9 flat).
//  * L0: 80 KB weights LDS + 32 KB stage = 112 KB.
//  * L1: W_ih1 (64 KB) in LDS; W_hh1 B-frags read per-step from global
//    (read-only, L1/L2-cached, off the coherence point).  Single 32 KB stage
//    buffer, double-staged via regs with partial vmcnt(4) wait.
//  * L0 drain-hide: next step's x-part MFMAs issued between epi stores and
//    the vmcnt(0) drain.

__global__ __launch_bounds__(NTHR, 1)
void k_lstm(const u16* __restrict__ xbf,
            const u16* __restrict__ wl0g, const u16* __restrict__ wl1g, const u16* __restrict__ wfcg,
            const float* __restrict__ bias0, const float* __restrict__ bias1, const float* __restrict__ fcb,
            u16* __restrict__ h0ring, u16* __restrict__ h1ring,
            u32* __restrict__ flags, float* __restrict__ dout)
{
    __shared__ u16   wlds[40960];                    // 80 KB weights (max role)
    __shared__ u32x4 hstage[2048];                   // 32 KB h staging
    const int tid  = threadIdx.x;
    const int lane = tid & 63;
    const int wv   = tid >> 6;                       // 0..7
    const int mt   = wv >> 2;                        // batch-half tile
    const int nc   = wv & 3;                         // col tile 0..3
    const int ci   = lane & 15;
    const int quad = lane >> 4;
    const int wg   = blockIdx.x;

    int role, rwg;
    if      (wg < L0_WGS)           { role = 0; rwg = wg; }
    else if (wg < L0_WGS + L1_WGS)  { role = 1; rwg = wg - L0_WGS; }
    else                            { role = 2; rwg = wg - L0_WGS - L1_WGS; }

    u32* flagL0 = flags;                             // [32] @64B stride
    u32* flagL1 = flags + 64 * 16;                   // [32]
    u32* flagFC = flags + 128 * 16;                  // [2]
    u32* myflag = (role == 0) ? (flagL0 + rwg * 16)
                : (role == 1) ? (flagL1 + rwg * 16) : (flagFC + rwg * 16);

    {   // stage this WG's LDS-resident weight slice (once)
        const u16* src = (role == 0) ? (wl0g + rwg * 40960)
                       : (role == 1) ? (wl1g + rwg * 65536)   // first 64 KB = W_ih1
                                     : (wfcg + rwg * 32768);
        const int n4 = (role == 0) ? 5120 : 4096;             // 16B units
        uint4* d4 = reinterpret_cast<uint4*>(wlds);
        const uint4* s4 = reinterpret_cast<const uint4*>(src);
        for (int i = tid; i < n4; i += NTHR) d4[i] = s4[i];
    }
    __syncthreads();

    const bf16x8* wp = reinterpret_cast<const bf16x8*>(wlds);
    const int wbase  = quad * 64 + nc * 16 + ci;     // + ks*256 (64-col layout)
    const int pcol   = rwg * 64 + nc * 16 + ci;      // permuted gate col / out col
    const int gateid = pcol & 3;                     // 0=i 1=f 2=g 3=o
    const float bias = (role == 0) ? bias0[pcol] : (role == 1) ? bias1[pcol] : fcb[pcol];
    const int brow0  = mt * 16 + quad * 4;           // C/D rows
    const int arow   = mt * 16 + ci;                 // A-frag batch row
    const int jidx   = pcol >> 2;                    // h index owned (roles 0/1)
    const int hfrag  = arow * 64 + quad;             // LDS chunk base
    const int hswz   = arow & 7;                     // row XOR swizzle

    float cst[4] = {0.f, 0.f, 0.f, 0.f};

    auto spin = [&](u32* f, int target) {
        if (target > 0)
            while ((int)__hip_atomic_load(f, __ATOMIC_RELAXED, __HIP_MEMORY_SCOPE_AGENT) < target)
                __builtin_amdgcn_s_sleep(1);
    };
    auto stf = [&](u32* f, u32 v) {
        __hip_atomic_store(f, v, __ATOMIC_RELAXED, __HIP_MEMORY_SCOPE_AGENT);
    };

    auto scat = [&](int c, u32x4 b) { hstage[c ^ ((c >> 6) & 7)] = b; };

    // full cooperative stage of one 32KB slot (2048 x 16B), 4 chunks/thread
    auto stage1 = [&](const u16* slot) {
        u32x4 b[4];
        #pragma unroll
        for (int r = 0; r < 4; ++r) b[r] = ld16_llc(slot + (tid + r * 512) * 8);
        wait_vm0();
        #pragma unroll
        for (int r = 0; r < 4; ++r) scat(tid + r * 512, b[r]);
    };

    // epilogue: gates -> c,h; shfl-transpose; 16 lanes store 1 u64 each
    auto epi = [&](const f32x4& acc, u16* slotb) {
        float ga[4], hv[4];
        #pragma unroll
        for (int r = 0; r < 4; ++r) {
            float g  = acc[r] + bias;
            float sv = 1.0f / (1.0f + __expf(-g));
            float tv = 1.0f - 2.0f / (__expf(2.0f * g) + 1.0f);
            ga[r] = (gateid == 2) ? tv : sv;
        }
        const int bl = lane & ~3;
        #pragma unroll
        for (int r = 0; r < 4; ++r) {
            float iv = __shfl(ga[r], bl + 0);
            float fv = __shfl(ga[r], bl + 1);
            float gv = __shfl(ga[r], bl + 2);
            float ov = __shfl(ga[r], bl + 3);
            float cn = fv * cst[r] + iv * gv;
            cst[r] = cn;
            hv[r] = ov * (1.0f - 2.0f / (__expf(2.0f * cn) + 1.0f));
        }
        u32 lo = 0, hi = 0;
        #pragma unroll
        for (int r = 0; r < 4; ++r) {                // gather row brow0+r into lane ci==r
            float c0 = __shfl(hv[r], (quad << 4) + 0);
            float c1 = __shfl(hv[r], (quad << 4) + 4);
            float c2 = __shfl(hv[r], (quad << 4) + 8);
            float c3 = __shfl(hv[r], (quad << 4) + 12);
            if (ci == r) {
                lo = (u32)f2bf(c0) | ((u32)f2bf(c1) << 16);
                hi = (u32)f2bf(c2) | ((u32)f2bf(c3) << 16);
            }
        }
        if (ci < 4) {
            u64* dst = reinterpret_cast<u64*>(slotb) + (brow0 + ci) * 128 + rwg * 4 + nc;
            u64 val = (u64)lo | ((u64)hi << 32);
            __hip_atomic_store(dst, val, __ATOMIC_RELAXED, __HIP_MEMORY_SCOPE_AGENT);
        }
    };

    // 16 MFMAs, B-frags from LDS weights (k-group stride 256 chunks)
    #define HMFMA16L(KSOFF)                                                      \
        _Pragma("unroll")                                                        \
        for (int _k = 0; _k < 16; ++_k) {                                        \
          u32x4 _hv = hstage[(hfrag + _k * 4) ^ hswz];                           \
          bf16x8 _bv = wp[wbase + (_k + (KSOFF)) * 256];                         \
          if (_k & 1) accB = __builtin_amdgcn_mfma_f32_16x16x32_bf16(as_bf(_hv), _bv, accB, 0, 0, 0); \
          else        accA = __builtin_amdgcn_mfma_f32_16x16x32_bf16(as_bf(_hv), _bv, accA, 0, 0, 0); \
        }

    auto fcTileS = [&]() -> f32x4 {                  // fc tile from staged h (with relu)
        f32x4 accA = {0.f,0.f,0.f,0.f}, accB = {0.f,0.f,0.f,0.f};
        #pragma unroll
        for (int ks = 0; ks < 16; ++ks) {
            u32x4 v = hstage[(hfrag + ks * 4) ^ hswz];
            v[0] = relu2(v[0]); v[1] = relu2(v[1]); v[2] = relu2(v[2]); v[3] = relu2(v[3]);
            bf16x8 bv = wp[wbase + ks * 256];
            if (ks & 1) accB = __builtin_amdgcn_mfma_f32_16x16x32_bf16(as_bf(v), bv, accB, 0, 0, 0);
            else        accA = __builtin_amdgcn_mfma_f32_16x16x32_bf16(as_bf(v), bv, accA, 0, 0, 0);
        }
        return accA + accB;
    };

    if (role == 0) {
        u32* pf = (tid < 32) ? (flagL0 + tid * 16)
                : (tid >= 64 && tid < 96) ? (flagL1 + (tid - 64) * 16) : nullptr;
        const int po = (tid < 32) ? 0 : -3;
        // x-part of step t into fresh accs (4 loads + 4 MFMAs, ks 16..19)
        auto xpart = [&](int t, f32x4& aA, f32x4& aB) {
            const u16* xA = xbf + (arow * T_STEPS + t) * INDIM + quad * 8;
            u32x4 xv[4];
            #pragma unroll
            for (int k4 = 0; k4 < 4; ++k4) xv[k4] = *reinterpret_cast<const u32x4*>(xA + k4 * 32);
            #pragma unroll
            for (int k4 = 0; k4 < 4; ++k4) {
                bf16x8 bv = wp[wbase + (16 + k4) * 256];
                if (k4 & 1) aB = __builtin_amdgcn_mfma_f32_16x16x32_bf16(as_bf(xv[k4]), bv, aB, 0, 0, 0);
                else        aA = __builtin_amdgcn_mfma_f32_16x16x32_bf16(as_bf(xv[k4]), bv, aA, 0, 0, 0);
            }
        };
        f32x4 xA0 = {0.f,0.f,0.f,0.f}, xB0 = {0.f,0.f,0.f,0.f};
        xpart(0, xA0, xB0);
        for (int t = 0; t < T_STEPS; ++t) {
            if (pf) spin(pf, t + po);
            __syncthreads();
            stage1(h0ring + ((t + 3) & 3) * BH);      // h0[t-1]
            __syncthreads();
            f32x4 accA = xA0, accB = xB0;
            HMFMA16L(0);
            epi(accA + accB, h0ring + (t & 3) * BH);
            if (t + 1 < T_STEPS) {                    // drain-hide: next x-part
                xA0 = (f32x4){0.f,0.f,0.f,0.f}; xB0 = (f32x4){0.f,0.f,0.f,0.f};
                xpart(t + 1, xA0, xB0);
            }
            vm0();                                    // h stores complete at LLC
            __syncthreads();
            if (tid == 0) stf(myflag, (u32)(t + 1));
        }
    } else if (role == 1) {
        u32* pf = (tid < 32)  ? (flagL0 + tid * 16)
                : (tid >= 64 && tid < 96) ? (flagL1 + (tid - 64) * 16)
                : (tid >= 128 && tid < 130) ? (flagFC + (tid - 128) * 16) : nullptr;
        const int po = (tid < 32) ? 1 : (tid < 96) ? 0 : -3;
        const u16* wB = wl1g + rwg * 65536 + 32768 + quad * 512 + (nc * 16 + ci) * 8;
        for (int t = 0; t < T_STEPS; ++t) {
            if (pf) spin(pf, t + po);
            __syncthreads();
            const u16* s0 = h0ring + (t & 3) * BH;            // h0[t]
            const u16* s1 = h1ring + ((t + 3) & 3) * BH;      // h1[t-1]
            u32x4 b0[4], b1[4];
            #pragma unroll
            for (int r = 0; r < 4; ++r) b0[r] = ld16_llc(s0 + (tid + r * 512) * 8);
            #pragma unroll
            for (int r = 0; r < 4; ++r) b1[r] = ld16_llc(s1 + (tid + r * 512) * 8);
            wait_vm4();                               // b0 arrived (b1 still in flight)
            #pragma unroll
            for (int r = 0; r < 4; ++r) scat(tid + r * 512, b0[r]);
            __syncthreads();
            f32x4 accA = {0.f,0.f,0.f,0.f}, accB = {0.f,0.f,0.f,0.f};
            HMFMA16L(0);                              // h0[t] x W_ih1 (LDS weights)
            __syncthreads();                          // all waves done with hstage(h0)
            wait_vm0();                               // b1 arrived (long since)
            #pragma unroll
            for (int r = 0; r < 4; ++r) scat(tid + r * 512, b1[r]);
            __syncthreads();
            #pragma unroll
            for (int _k = 0; _k < 16; ++_k) {         // h1[t-1] x W_hh1 (B from global/L2)
                u32x4 hv = hstage[(hfrag + _k * 4) ^ hswz];
                bf16x8 bv = *reinterpret_cast<const bf16x8*>(wB + _k * 2048);
                if (_k & 1) accB = __builtin_amdgcn_mfma_f32_16x16x32_bf16(as_bf(hv), bv, accB, 0, 0, 0);
                else        accA = __builtin_amdgcn_mfma_f32_16x16x32_bf16(as_bf(hv), bv, accA, 0, 0, 0);
            }
            epi(accA + accB, h1ring + (t & 3) * BH);
            vm0();
            __syncthreads();
            if (tid == 0) stf(myflag, (u32)(t + 1));
        }
    } else {
        u32* pf = (tid < 32) ? (flagL1 + tid * 16) : nullptr;
        for (int t = 0; t < T_STEPS; ++t) {
            if (pf) spin(pf, t + 1);
            __syncthreads();
            stage1(h1ring + (t & 3) * BH);
            __syncthreads();
            f32x4 acc = fcTileS();
            #pragma unroll
            for (int r = 0; r < 4; ++r)
                dout[((brow0 + r) * T_STEPS + t) * OUTD + pcol] = acc[r] + bias;
            __syncthreads();                          // all reads of slot done before flag
            if (tid == 0) stf(myflag, (u32)(t + 1));
        }
        // hidden = fc(relu(h_n)); hstage still holds h1[2047] (slot 3)
        f32x4 hh1 = fcTileS();
        __syncthreads();
        stage1(h0ring + 3 * BH);                      // h0[2047]
        __syncthreads();
        f32x4 hh0 = fcTileS();
        #pragma unroll
        for (int r = 0; r < 4; ++r)
            dout[HID_OFF + (brow0 + r) * OUTD + pcol] = hh0[r] + bias;
        #pragma unroll
        for (int r = 0; r < 4; ++r)
            dout[HID_OFF + (BATCH + brow0 + r) * OUTD + pcol] = hh1[r] + bias;
    }

    // c_n output [2, 32, 512]
    if (role <= 1 && (ci & 3) == 0) {
        #pragma unroll
        for (int r = 0; r < 4; ++r)
            dout[CN_OFF + (role * BATCH + brow0 + r) * HID + jidx] = cst[r];
    }
}

// ---------------- launch ----------------

extern "C" void kernel_launch(void* const* d_in, const int* in_sizes, int n_in,
                              void* d_out, int out_size, void* d_ws, size_t ws_size,
                              hipStream_t stream) {
    const float* x    = (const float*)d_in[0];
    const float* wih0 = (const float*)d_in[1];
    const float* whh0 = (const float*)d_in[2];
    const float* bih0 = (const float*)d_in[3];
    const float* bhh0 = (const float*)d_in[4];
    const float* wih1 = (const float*)d_in[5];
    const float* whh1 = (const float*)d_in[6];
    const float* bih1 = (const float*)d_in[7];
    const float* bhh1 = (const float*)d_in[8];
    const float* fcw  = (const float*)d_in[9];
    const float* fcb  = (const float*)d_in[10];

    char* ws = (char*)d_ws;
    u32*  flags = (u32*)(ws + WS_FLAGS);
    u16*  h0r   = (u16*)(ws + WS_H0RING);
    u16*  h1r   = (u16*)(ws + WS_H1RING);
    float* b0   = (float*)(ws + WS_BIAS0);
    float* b1   = (float*)(ws + WS_BIAS1);
    u16*  wfc   = (u16*)(ws + WS_WFC);
    u16*  wl0   = (u16*)(ws + WS_WL0);
    u16*  wl1   = (u16*)(ws + WS_WL1);
    u16*  xbf   = (u16*)(ws + WS_XBF);
    float* dout = (float*)d_out;

    // zero flags (16 KB) + h rings (256 KB)
    k_zero<<<272, 256, 0, stream>>>((u32*)ws, 69632);
    k_bias<<<8, 256, 0, stream>>>(bih0, bhh0, bih1, bhh1, b0, b1);
    k_xconv<<<8192, 256, 0, stream>>>(x, xbf);
    k_wconv<<<13568, 256, 0, stream>>>(wih0, whh0, wih1, whh1, fcw, wl0, wl1, wfc);
    k_lstm<<<NWG, NTHR, 0, stream>>>(xbf, wl0, wl1, wfc, b0, b1, fcb,
                                     h0r, h1r, flags, dout);
}

// Round 11
// 9252.466 us; speedup vs baseline: 1.1433x; 1.1433x over previous
//
#include <hip/hip_runtime.h>

typedef unsigned int u32;
typedef unsigned short u16;
typedef unsigned long long u64;

#define T_STEPS 2048
#define BATCH   32
#define HID     512
#define INDIM   128
#define OUTD    128
#define NG      2048
#define L0_WGS  64
#define L1_WGS  64
#define FC_WGS  4
#define NWG     (L0_WGS + L1_WGS + FC_WGS)
#define BH      (BATCH * HID)

#define HID_OFF 8388608           // 32*2048*128
#define CN_OFF  8396800           // + 2*32*128

// ws layout (bytes) — identical to v5
#define WS_FLAGS   0                         // 132 flags, 64B stride (16 KB reserved)
#define WS_H0RING  16384
#define WS_H1RING  (WS_H0RING + 131072)      // 4*32*512*2
#define WS_BIAS0   (WS_H1RING + 131072)
#define WS_BIAS1   (WS_BIAS0 + 8192)
#define WS_WFC     (WS_BIAS1 + 8192)         // 4 * 16384 u16
#define WS_WL0     (WS_WFC + 131072)         // 64 * 20480 u16
#define WS_WL1     (WS_WL0 + 2621440)        // 64 * 32768 u16
#define WS_XBF     (WS_WL1 + 4194304)        // 32*2048*128 u16

typedef __bf16 bf16x8 __attribute__((ext_vector_type(8)));
typedef float  f32x4  __attribute__((ext_vector_type(4)));
typedef unsigned int u32x4 __attribute__((ext_vector_type(4)));

__device__ __forceinline__ u16 f2bf(float f) {
    u32 u = __float_as_uint(f);
    u32 r = u + 0x7FFFu + ((u >> 16) & 1u);
    return (u16)(r >> 16);
}

union UB2 { u32x4 u; bf16x8 b; };
__device__ __forceinline__ bf16x8 as_bf(u32x4 u) { UB2 x; x.u = u; return x.b; }

__device__ __forceinline__ u32 relu2(u32 u) {
    u32 lo = (u & 0x8000u)     ? 0u : (u & 0xFFFFu);
    u32 hi = (u & 0x80000000u) ? 0u : (u & 0xFFFF0000u);
    return lo | hi;
}

// 16B LLC-bypass load (sc0 sc1). NON-atomic; caller waits vmcnt before use.
__device__ __forceinline__ u32x4 ld16_llc(const void* p) {
    u32x4 r;
    asm volatile("global_load_dwordx4 %0, %1, off sc0 sc1"
                 : "=v"(r) : "v"(p) : "memory");
    return r;
}
__device__ __forceinline__ void wait_vm0() {
    asm volatile("s_waitcnt vmcnt(0)" ::: "memory");
    __builtin_amdgcn_sched_barrier(0);
}
__device__ __forceinline__ void vm0() {          // drain own stores to coherence point
    asm volatile("s_waitcnt vmcnt(0)" ::: "memory");
}

// ---------------- prep kernels (unchanged from v5) ----------------

__global__ void k_zero(u32* dst, int n) {
    int i = blockIdx.x * blockDim.x + threadIdx.x;
    if (i < n) dst[i] = 0u;
}

__global__ void k_bias(const float* __restrict__ bih0, const float* __restrict__ bhh0,
                       const float* __restrict__ bih1, const float* __restrict__ bhh1,
                       float* __restrict__ bias0, float* __restrict__ bias1) {
    int i = blockIdx.x * blockDim.x + threadIdx.x;
    if (i < NG) {
        int orig = (i & 3) * HID + (i >> 2);
        bias0[i] = bih0[orig] + bhh0[orig];
        bias1[i] = bih1[orig] + bhh1[orig];
    }
}

__global__ void k_xconv(const float* __restrict__ x, u16* __restrict__ xbf) {
    int i = blockIdx.x * blockDim.x + threadIdx.x;   // exactly 2097152 threads
    float4 v = reinterpret_cast<const float4*>(x)[i];
    u32 lo = (u32)f2bf(v.x) | ((u32)f2bf(v.y) << 16);
    u32 hi = (u32)f2bf(v.z) | ((u32)f2bf(v.w) << 16);
    reinterpret_cast<uint2*>(xbf)[i] = make_uint2(lo, hi);
}

// LDS-ready layout per WG: [ks][kb(4)][n(32)][8], value = W[p = wg*32+n][k = 32ks+8kb+j]
__global__ void k_wconv(const float* __restrict__ wih0, const float* __restrict__ whh0,
                        const float* __restrict__ wih1, const float* __restrict__ whh1,
                        const float* __restrict__ fcw,
                        u16* __restrict__ wl0, u16* __restrict__ wl1, u16* __restrict__ wfc) {
    int i = blockIdx.x * blockDim.x + threadIdx.x;   // exactly 3473408 threads
    if (i < 64 * 20480) {                            // layer0: K=640 (512 hh + 128 ih)
        int wg = i / 20480, r = i % 20480;
        int ks = r / 1024, kb = (r % 1024) / 256, n = (r % 256) / 8, j = r % 8;
        int k = ks * 32 + kb * 8 + j;
        int p = wg * 32 + n;
        int orig = (p & 3) * HID + (p >> 2);
        float v = (k < HID) ? whh0[orig * HID + k] : wih0[orig * INDIM + (k - HID)];
        wl0[i] = f2bf(v);
        return;
    }
    int i1 = i - 64 * 20480;
    if (i1 < 64 * 32768) {                           // layer1: K=1024 (512 ih(h0) + 512 hh(h1))
        int wg = i1 / 32768, r = i1 % 32768;
        int ks = r / 1024, kb = (r % 1024) / 256, n = (r % 256) / 8, j = r % 8;
        int k = ks * 32 + kb * 8 + j;
        int p = wg * 32 + n;
        int orig = (p & 3) * HID + (p >> 2);
        float v = (k < HID) ? wih1[orig * HID + k] : whh1[orig * HID + (k - HID)];
        wl1[i1] = f2bf(v);
        return;
    }
    int i2 = i1 - 64 * 32768;
    if (i2 < 4 * 16384) {                            // fc: K=512, no row permutation
        int wg = i2 / 16384, r = i2 % 16384;
        int ks = r / 1024, kb = (r % 1024) / 256, n = (r % 256) / 8, j = r % 8;
        int k = ks * 32 + kb * 8 + j;
        int o = wg * 32 + n;
        wfc[i2] = f2bf(fcw[o * HID + k]);
    }
}

// ---------------- persistent fused LSTM ----------------
//
// v5 protocol + data path EXACTLY (proven 8.89 ms).  Chain-leg trims only:
//  * spins distributed per-thread (lane tid&63 polls its producer) — same
//    flag targets, enables phased load issue.
//  * L1 two-phase stage: spin h1[t-1] flags (usually long set) -> issue h1
//    loads -> spin h0[t] flags (h1 loads fly underneath) -> issue h0 loads
//    -> ONE drain.  Removes the h1 half of L1's stage from the serial cycle.
//  * L0 drain-hide: next step's x-part (loads+4 MFMAs) issued between epi
//    stores and the vmcnt(0) drain.

__global__ __launch_bounds__(256, 1)
void k_lstm(const u16* __restrict__ xbf,
            const u16* __restrict__ wl0g, const u16* __restrict__ wl1g, const u16* __restrict__ wfcg,
            const float* __restrict__ bias0, const float* __restrict__ bias1, const float* __restrict__ fcb,
            u16* __restrict__ h0ring, u16* __restrict__ h1ring,
            u32* __restrict__ flags, float* __restrict__ dout)
{
    __shared__ u16   wlds[32768];                    // 64 KB weights
    __shared__ u32x4 hstage[2][2048];                // 2 x 32 KB h staging
    const int tid  = threadIdx.x;
    const int lane = tid & 63;
    const int wv   = tid >> 6;
    const int mt   = wv >> 1;                        // batch-half tile
    const int nt   = wv & 1;                         // col tile
    const int ci   = lane & 15;
    const int quad = lane >> 4;
    const int wg   = blockIdx.x;

    int role, rwg;
    if      (wg < L0_WGS)           { role = 0; rwg = wg; }
    else if (wg < L0_WGS + L1_WGS)  { role = 1; rwg = wg - L0_WGS; }
    else                            { role = 2; rwg = wg - L0_WGS - L1_WGS; }

    u32* flagL0 = flags;
    u32* flagL1 = flags + 64 * 16;
    u32* flagFC = flags + 128 * 16;
    u32* myflag = flags + wg * 16;

    {   // stage this WG's weight slice into LDS (once)
        const u16* src = (role == 0) ? (wl0g + rwg * 20480)
                       : (role == 1) ? (wl1g + rwg * 32768)
                                     : (wfcg + rwg * 16384);
        const int n4 = (role == 0) ? 2560 : (role == 1) ? 4096 : 2048;
        uint4* d4 = reinterpret_cast<uint4*>(wlds);
        const uint4* s4 = reinterpret_cast<const uint4*>(src);
        for (int i = tid; i < n4; i += 256) d4[i] = s4[i];
    }
    __syncthreads();

    const bf16x8* wp = reinterpret_cast<const bf16x8*>(wlds);
    const int wbase  = quad * 32 + nt * 16 + ci;     // + ks*128
    const int pcol   = rwg * 32 + nt * 16 + ci;      // permuted gate col (roles 0/1) or out col (fc)
    const int gateid = pcol & 3;                     // 0=i 1=f 2=g 3=o
    const float bias = (role == 0) ? bias0[pcol] : (role == 1) ? bias1[pcol] : fcb[pcol];
    const int brow0  = mt * 16 + quad * 4;           // C/D: batch of acc reg r is brow0+r
    const int arow   = mt * 16 + ci;                 // A-frag batch row
    const int jidx   = pcol >> 2;                    // h index owned (roles 0/1)
    const int hfrag  = arow * 64 + quad;             // LDS chunk base for fragments
    const int hswz   = arow & 7;                     // row XOR swizzle

    float cst[4] = {0.f, 0.f, 0.f, 0.f};             // c-state, f32, replicated x4 lanes

    auto spin = [&](u32* f, int target) {
        if (target > 0)
            while ((int)__hip_atomic_load(f, __ATOMIC_RELAXED, __HIP_MEMORY_SCOPE_AGENT) < target)
                __builtin_amdgcn_s_sleep(1);
    };
    auto stf = [&](u32* f, u32 v) {
        __hip_atomic_store(f, v, __ATOMIC_RELAXED, __HIP_MEMORY_SCOPE_AGENT);
    };

    auto scat = [&](int buf, u32x4* b) {             // scatter 8 chunks into LDS
        #pragma unroll
        for (int r = 0; r < 8; ++r) {
            int c = tid + r * 256;
            hstage[buf][c ^ ((c >> 6) & 7)] = b[r];
        }
    };

    // cooperative LLC->LDS stage of one 32KB slot (2048 x 16B), 8 chunks/thread
    auto stage1 = [&](const u16* slot, int buf) {
        u32x4 b[8];
        #pragma unroll
        for (int r = 0; r < 8; ++r) b[r] = ld16_llc(slot + (tid + r * 256) * 8);
        wait_vm0();
        scat(buf, b);
    };

    // epilogue: gates -> c,h; shfl-transpose; one aligned 8B agent store per active lane
    auto epi = [&](const f32x4& acc, u16* slotb) {
        float ga[4], hv[4];
        #pragma unroll
        for (int r = 0; r < 4; ++r) {
            float g  = acc[r] + bias;
            float sv = 1.0f / (1.0f + __expf(-g));
            float tv = 1.0f - 2.0f / (__expf(2.0f * g) + 1.0f);
            ga[r] = (gateid == 2) ? tv : sv;
        }
        const int bl = lane & ~3;
        #pragma unroll
        for (int r = 0; r < 4; ++r) {
            float iv = __shfl(ga[r], bl + 0);
            float fv = __shfl(ga[r], bl + 1);
            float gv = __shfl(ga[r], bl + 2);
            float ov = __shfl(ga[r], bl + 3);
            float cn = fv * cst[r] + iv * gv;
            cst[r] = cn;
            hv[r] = ov * (1.0f - 2.0f / (__expf(2.0f * cn) + 1.0f));
        }
        u32 lo = 0, hi = 0;
        #pragma unroll
        for (int r = 0; r < 4; ++r) {                // gather row brow0+r into lane ci==r
            float c0 = __shfl(hv[r], (quad << 4) + 0);   // jidx = rwg*8+nt*4+0
            float c1 = __shfl(hv[r], (quad << 4) + 4);   // +1
            float c2 = __shfl(hv[r], (quad << 4) + 8);   // +2
            float c3 = __shfl(hv[r], (quad << 4) + 12);  // +3
            if (ci == r) {
                lo = (u32)f2bf(c0) | ((u32)f2bf(c1) << 16);
                hi = (u32)f2bf(c2) | ((u32)f2bf(c3) << 16);
            }
        }
        if (ci < 4) {
            u64* dst = reinterpret_cast<u64*>(slotb) + (brow0 + ci) * 128 + rwg * 2 + nt;
            u64 val = (u64)lo | ((u64)hi << 32);
            __hip_atomic_store(dst, val, __ATOMIC_RELAXED, __HIP_MEMORY_SCOPE_AGENT);
        }
    };

    // 16 MFMAs with A-fragments from LDS stage buffer
    #define HMFMA16S(BUF, KSOFF)                                                 \
        _Pragma("unroll")                                                        \
        for (int _k = 0; _k < 16; ++_k) {                                        \
          u32x4 _hv = hstage[BUF][(hfrag + _k * 4) ^ hswz];                      \
          bf16x8 _bv = wp[wbase + (_k + (KSOFF)) * 128];                         \
          if (_k & 1) accB = __builtin_amdgcn_mfma_f32_16x16x32_bf16(as_bf(_hv), _bv, accB, 0, 0, 0); \
          else        accA = __builtin_amdgcn_mfma_f32_16x16x32_bf16(as_bf(_hv), _bv, accA, 0, 0, 0); \
        }

    auto fcTileS = [&](int buf) -> f32x4 {           // fc tile from staged h (with relu)
        f32x4 accA = {0.f,0.f,0.f,0.f}, accB = {0.f,0.f,0.f,0.f};
        #pragma unroll
        for (int ks = 0; ks < 16; ++ks) {
            u32x4 v = hstage[buf][(hfrag + ks * 4) ^ hswz];
            v[0] = relu2(v[0]); v[1] = relu2(v[1]); v[2] = relu2(v[2]); v[3] = relu2(v[3]);
            bf16x8 bv = wp[wbase + ks * 128];
            if (ks & 1) accB = __builtin_amdgcn_mfma_f32_16x16x32_bf16(as_bf(v), bv, accB, 0, 0, 0);
            else        accA = __builtin_amdgcn_mfma_f32_16x16x32_bf16(as_bf(v), bv, accA, 0, 0, 0);
        }
        return accA + accB;
    };

    if (role == 0) {
        // x-part of step t (4 loads + 4 MFMAs, ks 16..19) into persistent accs
        f32x4 xA0 = {0.f,0.f,0.f,0.f}, xB0 = {0.f,0.f,0.f,0.f};
        auto xpart = [&](int t) {
            const u16* xA = xbf + (arow * T_STEPS + t) * INDIM + quad * 8;
            u32x4 xv[4];
            #pragma unroll
            for (int k4 = 0; k4 < 4; ++k4) xv[k4] = *reinterpret_cast<const u32x4*>(xA + k4 * 32);
            #pragma unroll
            for (int k4 = 0; k4 < 4; ++k4) {
                bf16x8 bv = wp[wbase + (16 + k4) * 128];
                if (k4 & 1) xB0 = __builtin_amdgcn_mfma_f32_16x16x32_bf16(as_bf(xv[k4]), bv, xB0, 0, 0, 0);
                else        xA0 = __builtin_amdgcn_mfma_f32_16x16x32_bf16(as_bf(xv[k4]), bv, xA0, 0, 0, 0);
            }
        };
        xpart(0);
        for (int t = 0; t < T_STEPS; ++t) {
            // h0[t-1] ready: every thread polls its own producer's flag
            spin(flagL0 + lane * 16, t);
            u32x4 b[8];
            const u16* hA = h0ring + ((t + 3) & 3) * BH;
            #pragma unroll
            for (int r = 0; r < 8; ++r) b[r] = ld16_llc(hA + (tid + r * 256) * 8);
            if (tid >= 64 && tid < 128)               // WAR: loads fly underneath
                spin(flagL1 + (tid - 64) * 16, t - 3);
            wait_vm0();
            scat(0, b);
            __syncthreads();
            f32x4 accA = xA0, accB = xB0;
            HMFMA16S(0, 0);
            epi(accA + accB, h0ring + (t & 3) * BH);
            if (t + 1 < T_STEPS) {                    // drain-hide: next x-part
                xA0 = (f32x4){0.f,0.f,0.f,0.f}; xB0 = (f32x4){0.f,0.f,0.f,0.f};
                xpart(t + 1);
            }
            vm0();                                    // h stores complete at LLC
            __syncthreads();
            if (tid == 0) stf(myflag, (u32)(t + 1));
        }
    } else if (role == 1) {
        for (int t = 0; t < T_STEPS; ++t) {
            // phase A: h1[t-1] (own role, step t-1 — usually long set)
            spin(flagL1 + lane * 16, t);
            u32x4 b1[8];
            const u16* s1 = h1ring + ((t + 3) & 3) * BH;
            #pragma unroll
            for (int r = 0; r < 8; ++r) b1[r] = ld16_llc(s1 + (tid + r * 256) * 8);
            if (tid >= 128 && tid < 132)              // FC WAR on h1 ring
                spin(flagFC + (tid - 128) * 16, t - 3);
            // phase B: h0[t] (the laggard) — b1 loads fly during this spin
            spin(flagL0 + lane * 16, t + 1);
            u32x4 b0[8];
            const u16* s0 = h0ring + (t & 3) * BH;
            #pragma unroll
            for (int r = 0; r < 8; ++r) b0[r] = ld16_llc(s0 + (tid + r * 256) * 8);
            wait_vm0();
            scat(0, b0);
            scat(1, b1);
            __syncthreads();
            f32x4 accA = {0.f, 0.f, 0.f, 0.f}, accB = {0.f, 0.f, 0.f, 0.f};
            HMFMA16S(0, 0);                           // K 0..511: h0[t] (W_ih1)
            HMFMA16S(1, 16);                          // K 512..1023: h1[t-1] (W_hh1)
            epi(accA + accB, h1ring + (t & 3) * BH);
            vm0();                                    // h stores complete at LLC
            __syncthreads();
            if (tid == 0) stf(myflag, (u32)(t + 1));
        }
    } else {
        for (int t = 0; t < T_STEPS; ++t) {
            spin(flagL1 + lane * 16, t + 1);
            __syncthreads();
            stage1(h1ring + (t & 3) * BH, 0);
            __syncthreads();
            f32x4 acc = fcTileS(0);
            #pragma unroll
            for (int r = 0; r < 4; ++r)
                dout[((brow0 + r) * T_STEPS + t) * OUTD + pcol] = acc[r] + bias;
            __syncthreads();                          // all reads of slot done before flag
            if (tid == 0) stf(myflag, (u32)(t + 1));
        }
        // hidden = fc(relu(h_n)); h[T-1] lives in slot 3 of each ring (2047 & 3 == 3).
        // hstage[0] still holds h1[2047] from the last loop iteration.
        stage1(h0ring + 3 * BH, 1);
        __syncthreads();
        f32x4 hh1 = fcTileS(0);
        f32x4 hh0 = fcTileS(1);
        #pragma unroll
        for (int r = 0; r < 4; ++r)
            dout[HID_OFF + (brow0 + r) * OUTD + pcol] = hh0[r] + bias;
        #pragma unroll
        for (int r = 0; r < 4; ++r)
            dout[HID_OFF + (BATCH + brow0 + r) * OUTD + pcol] = hh1[r] + bias;
    }

    // c_n output [2, 32, 512]
    if (role <= 1 && (ci & 3) == 0) {
        #pragma unroll
        for (int r = 0; r < 4; ++r)
            dout[CN_OFF + (role * BATCH + brow0 + r) * HID + jidx] = cst[r];
    }
}

// ---------------- launch ----------------

extern "C" void kernel_launch(void* const* d_in, const int* in_sizes, int n_in,
                              void* d_out, int out_size, void* d_ws, size_t ws_size,
                              hipStream_t stream) {
    const float* x    = (const float*)d_in[0];
    const float* wih0 = (const float*)d_in[1];
    const float* whh0 = (const float*)d_in[2];
    const float* bih0 = (const float*)d_in[3];
    const float* bhh0 = (const float*)d_in[4];
    const float* wih1 = (const float*)d_in[5];
    const float* whh1 = (const float*)d_in[6];
    const float* bih1 = (const float*)d_in[7];
    const float* bhh1 = (const float*)d_in[8];
    const float* fcw  = (const float*)d_in[9];
    const float* fcb  = (const float*)d_in[10];

    char* ws = (char*)d_ws;
    u32*  flags = (u32*)(ws + WS_FLAGS);
    u16*  h0r   = (u16*)(ws + WS_H0RING);
    u16*  h1r   = (u16*)(ws + WS_H1RING);
    float* b0   = (float*)(ws + WS_BIAS0);
    float* b1   = (float*)(ws + WS_BIAS1);
    u16*  wfc   = (u16*)(ws + WS_WFC);
    u16*  wl0   = (u16*)(ws + WS_WL0);
    u16*  wl1   = (u16*)(ws + WS_WL1);
    u16*  xbf   = (u16*)(ws + WS_XBF);
    float* dout = (float*)d_out;

    // zero flags + h rings (ws is re-poisoned before every timed call)
    k_zero<<<272, 256, 0, stream>>>((u32*)ws, 69632);
    k_bias<<<8, 256, 0, stream>>>(bih0, bhh0, bih1, bhh1, b0, b1);
    k_xconv<<<8192, 256, 0, stream>>>(x, xbf);
    k_wconv<<<13568, 256, 0, stream>>>(wih0, whh0, wih1, whh1, fcw, wl0, wl1, wfc);
    k_lstm<<<NWG, 256, 0, stream>>>(xbf, wl0, wl1, wfc, b0, b1, fcb,
                                    h0r, h1r, flags, dout);
}